// Round 7
// baseline (269.437 us; speedup 1.0000x reference)
//
#include <hip/hip_runtime.h>
#include <hip/hip_bf16.h>

#define DDIM 1024
#define BATCH 8
#define SEQ 4096
#define MROWS (BATCH*SEQ)

typedef __attribute__((ext_vector_type(8))) short short8;
typedef __attribute__((ext_vector_type(4))) float floatx4;

// manual f32 -> bf16 round-to-nearest-even (finite inputs only)
__device__ inline short f2bf(float f) {
    unsigned int u = __builtin_bit_cast(unsigned int, f);
    unsigned int r = (u + 0x7fffu + ((u >> 16) & 1u)) >> 16;
    return (short)r;
}
__device__ inline float bf2f(short s) {
    unsigned int u = ((unsigned int)(unsigned short)s) << 16;
    return __builtin_bit_cast(float, u);
}
__device__ inline short8 pack8(float4 a, float4 b) {
    short8 v;
    v[0]=f2bf(a.x); v[1]=f2bf(a.y); v[2]=f2bf(a.z); v[3]=f2bf(a.w);
    v[4]=f2bf(b.x); v[5]=f2bf(b.y); v[6]=f2bf(b.z); v[7]=f2bf(b.w);
    return v;
}

__device__ inline float fast_tanh(float x) {
    float e = __expf(2.f * x);          // overflow->inf fine: 1-2/inf = 1
    return 1.f - 2.f / (e + 1.f);
}

typedef const __attribute__((address_space(1))) unsigned int* gas_ptr;
typedef __attribute__((address_space(3))) unsigned int* las_ptr;
__device__ __forceinline__ void gl16(const short* g, short* l) {
    __builtin_amdgcn_global_load_lds((gas_ptr)g, (las_ptr)l, 16, 0, 0);
}

#define VMCNT4 asm volatile("s_waitcnt vmcnt(4)" ::: "memory")
#define VMCNT6 asm volatile("s_waitcnt vmcnt(6)" ::: "memory")
#define VMCNT0 asm volatile("s_waitcnt vmcnt(0)" ::: "memory")
#define LGKM0  asm volatile("s_waitcnt lgkmcnt(0)" ::: "memory")
#define BARRIER do { __builtin_amdgcn_sched_barrier(0); __builtin_amdgcn_s_barrier(); \
                     __builtin_amdgcn_sched_barrier(0); } while (0)

// ---------------- prep: W1^T->bf16 | V^T->bf16 | hk ----------------
// blocks [0,1024): W1T; [1024,2048): VT; [2048,2176): hk
__global__ __launch_bounds__(256) void prep_kernel(const float* __restrict__ W1,
                                                   short* __restrict__ W1T,
                                                   const float* __restrict__ V,
                                                   short* __restrict__ VT,
                                                   const float* __restrict__ k,
                                                   const float* __restrict__ W2,
                                                   float* __restrict__ hk) {
    int bid = blockIdx.x;
    if (bid < 2048) {
        const float* src = (bid < 1024) ? W1 : V;
        short* dst = (bid < 1024) ? W1T : VT;
        int tb = bid & 1023;
        __shared__ float t[32][33];
        int bx = tb & 31, by = tb >> 5;
        int c  = threadIdx.x & 31;
        int r0 = threadIdx.x >> 5;
        for (int p = 0; p < 4; ++p) {
            int r = p * 8 + r0;
            t[r][c] = src[(size_t)(by * 32 + r) * DDIM + bx * 32 + c];
        }
        __syncthreads();
        for (int p = 0; p < 4; ++p) {
            int r = p * 8 + r0;
            dst[(size_t)(bx * 32 + r) * DDIM + by * 32 + c] = f2bf(t[c][r]);
        }
    } else {
        int hb = bid - 2048;
        int b  = hb >> 4;
        int h0 = (hb & 15) * 64;
        int hl = threadIdx.x & 63;
        int dc = threadIdx.x >> 6;
        const float* kb = k + (size_t)b * DDIM;
        float sum = 0.f;
        for (int d = dc * 256; d < dc * 256 + 256; ++d)
            sum += kb[d] * W2[(size_t)d * DDIM + h0 + hl];
        __shared__ float red[4][64];
        red[dc][hl] = sum;
        __syncthreads();
        if (dc == 0)
            hk[(size_t)b * DDIM + h0 + hl] = red[0][hl] + red[1][hl] + red[2][hl] + red[3][hl];
    }
}

// ---------------- 256x256 8-wave phase-split GEMM with counted vmcnt ----------------
// C[m][n] = sum_k A[m][k] * Bt[n][k].
// EPI==0: A = q (f32) reg-staged with inline f32->bf16 convert; nt==0 blocks also
//         write the converted A to qbf (full coverage: swizzle is per-row bijection).
//         out = H (bf16) = tanh(acc + hk[b][n]).
// EPI==1: A = H (bf16) via global_load_lds; out = E (bf16) = exp(acc).
template<int EPI>
__global__ __launch_bounds__(512, 2) void gemm256_kernel(const void* __restrict__ Aptr,
                                                         const short* __restrict__ Bt,
                                                         const float* __restrict__ hk,
                                                         short* __restrict__ Out,
                                                         short* __restrict__ qbf) {
    __shared__ __align__(16) short lds[2 * 32768];
    int bid = blockIdx.x;                 // 512 blocks, 512 % 8 == 0
    int swz = (bid & 7) * 64 + (bid >> 3);
    int mt = swz >> 2, nt = swz & 3;
    int m0 = mt * 256, n0 = nt * 256;
    int tid = threadIdx.x, lane = tid & 63, wid = tid >> 6;
    int wm = (wid >> 2) * 16;             // 0 | 16
    int wn = (wid & 3) * 16;              // 0,16,32,48
    int lr = lane & 15, kb = lane >> 4;   // kb 0..3
    floatx4 acc[8][4] = {};               // [mi][ni]

    const short* Abf = (const short*)Aptr;
    const float* Af  = (const float*)Aptr;
    const bool donate = (EPI == 0) && (nt == 0);

    int srow = lane >> 3;                 // 0..7
    int sblk = (lane & 7) ^ srow;         // pre-swizzled 16B source block
    const size_t arow_base = (size_t)(m0 + wid * 8 + srow) * DDIM + sblk * 8;
    const size_t brow_base = (size_t)(n0 + wid * 8 + srow) * DDIM + sblk * 8;
    const int lds_st = wid * 512 + lane * 8;

    float4 fA0[2][2], fA1[2][2];          // reg-staged A halves (EPI==0)

    auto stageA16 = [&](int buf, int h, int t) {      // EPI1 A via gl16
        #pragma unroll
        for (int r = 0; r < 2; ++r)
            gl16(Abf + arow_base + (size_t)(h * 128 + r * 64) * DDIM + t * 64,
                 lds + buf * 32768 + h * 8192 + r * 4096 + lds_st);
    };
    auto stageB = [&](int buf, int h, int t) {
        #pragma unroll
        for (int r = 0; r < 2; ++r)
            gl16(Bt + brow_base + (size_t)(h * 128 + r * 64) * DDIM + t * 64,
                 lds + buf * 32768 + 16384 + h * 8192 + r * 4096 + lds_st);
    };
    auto loadA = [&](float4 (&f)[2][2], int h, int t) {   // EPI0: issue f32 loads
        #pragma unroll
        for (int r = 0; r < 2; ++r) {
            const float* s = Af + arow_base + (size_t)(h * 128 + r * 64) * DDIM + t * 64;
            f[r][0] = *(const float4*)s;
            f[r][1] = *(const float4*)(s + 4);
        }
    };
    auto writeA = [&](float4 (&f)[2][2], int buf, int h, int t) { // EPI0: cvt + LDS (+donate)
        #pragma unroll
        for (int r = 0; r < 2; ++r) {
            short8 v = pack8(f[r][0], f[r][1]);
            *(short8*)(lds + buf * 32768 + h * 8192 + r * 4096 + lds_st) = v;
            if (donate)
                *(short8*)(qbf + arow_base + (size_t)(h * 128 + r * 64) * DDIM + t * 64) = v;
        }
    };
    auto rdA = [&](int buf, int mi, int kk) -> short8 {
        int row = wm + mi * 32 + lr;
        return *(const short8*)(lds + buf * 32768 + (row >> 7) * 8192 +
                                (row & 127) * 64 + (((kk * 4 + kb) ^ (row & 7)) * 8));
    };
    auto rdB = [&](int buf, int ni, int kk) -> short8 {
        int row = wn + ni * 64 + lr;
        return *(const short8*)(lds + buf * 32768 + 16384 + (row >> 7) * 8192 +
                                (row & 127) * 64 + (((kk * 4 + kb) ^ (row & 7)) * 8));
    };

    // prologue: tile 0 halves; ledger: A0,B0 retired before barrier, B1/A1 in flight
    if constexpr (EPI == 0) {
        loadA(fA0, 0, 0); stageB(0, 0, 0); stageB(0, 1, 0); loadA(fA1, 1, 0);
        VMCNT6;                       // retire A0(4),B0(2); leave B1(2)+A1(4)
        writeA(fA0, 0, 0, 0);
        LGKM0;
    } else {
        stageA16(0, 0, 0); stageB(0, 0, 0); stageB(0, 1, 0); stageA16(0, 1, 0);
        VMCNT4;                       // retire A0,B0; leave B1,A1
    }
    BARRIER;

    short8 a0[4][2], a1[4][2], b0[2][2], b1[2][2];

    for (int t = 0; t < 15; ++t) {
        int cb = t & 1, nb = cb ^ 1;
        // ---- P1: quadrant (mi0-3 x ni0-1), issue A0(t+1) ----
        if constexpr (EPI == 0) loadA(fA0, 0, t + 1); else stageA16(nb, 0, t + 1);
        #pragma unroll
        for (int mi = 0; mi < 4; ++mi)
            #pragma unroll
            for (int kk = 0; kk < 2; ++kk) a0[mi][kk] = rdA(cb, mi, kk);
        #pragma unroll
        for (int ni = 0; ni < 2; ++ni)
            #pragma unroll
            for (int kk = 0; kk < 2; ++kk) b0[ni][kk] = rdB(cb, ni, kk);
        __builtin_amdgcn_s_setprio(1);
        #pragma unroll
        for (int mi = 0; mi < 4; ++mi)
            #pragma unroll
            for (int ni = 0; ni < 2; ++ni)
                #pragma unroll
                for (int kk = 0; kk < 2; ++kk)
                    acc[mi][ni] = __builtin_amdgcn_mfma_f32_16x16x32_bf16(a0[mi][kk], b0[ni][kk], acc[mi][ni], 0, 0, 0);
        __builtin_amdgcn_s_setprio(0);
        VMCNT4;   // EPI0: retires B1(t)+A1(t) (and older stores); EPI1: retires B1(t)
        if constexpr (EPI == 0) { writeA(fA1, cb, 1, t); LGKM0; }
        BARRIER;
        // ---- P2: quadrant (mi0-3 x ni2-3), stage B0(t+1) ----
        stageB(nb, 0, t + 1);
        #pragma unroll
        for (int ni = 0; ni < 2; ++ni)
            #pragma unroll
            for (int kk = 0; kk < 2; ++kk) b1[ni][kk] = rdB(cb, ni + 2, kk);
        __builtin_amdgcn_s_setprio(1);
        #pragma unroll
        for (int mi = 0; mi < 4; ++mi)
            #pragma unroll
            for (int ni = 0; ni < 2; ++ni)
                #pragma unroll
                for (int kk = 0; kk < 2; ++kk)
                    acc[mi][ni + 2] = __builtin_amdgcn_mfma_f32_16x16x32_bf16(a0[mi][kk], b1[ni][kk], acc[mi][ni + 2], 0, 0, 0);
        __builtin_amdgcn_s_setprio(0);
        if constexpr (EPI == 1) VMCNT4;   // retires A1(t) (gl16, needed P3)
        BARRIER;
        // ---- P3: quadrant (mi4-7 x ni0-1), stage B1(t+1) ----
        stageB(nb, 1, t + 1);
        #pragma unroll
        for (int mi = 0; mi < 4; ++mi)
            #pragma unroll
            for (int kk = 0; kk < 2; ++kk) a1[mi][kk] = rdA(cb, mi + 4, kk);
        __builtin_amdgcn_s_setprio(1);
        #pragma unroll
        for (int mi = 0; mi < 4; ++mi)
            #pragma unroll
            for (int ni = 0; ni < 2; ++ni)
                #pragma unroll
                for (int kk = 0; kk < 2; ++kk)
                    acc[mi + 4][ni] = __builtin_amdgcn_mfma_f32_16x16x32_bf16(a1[mi][kk], b0[ni][kk], acc[mi + 4][ni], 0, 0, 0);
        __builtin_amdgcn_s_setprio(0);
        BARRIER;
        // ---- P4: quadrant (mi4-7 x ni2-3), issue A1(t+1) ----
        if constexpr (EPI == 0) loadA(fA1, 1, t + 1); else stageA16(nb, 1, t + 1);
        __builtin_amdgcn_s_setprio(1);
        #pragma unroll
        for (int mi = 0; mi < 4; ++mi)
            #pragma unroll
            for (int ni = 0; ni < 2; ++ni)
                #pragma unroll
                for (int kk = 0; kk < 2; ++kk)
                    acc[mi + 4][ni + 2] = __builtin_amdgcn_mfma_f32_16x16x32_bf16(a1[mi][kk], b1[ni][kk], acc[mi + 4][ni + 2], 0, 0, 0);
        __builtin_amdgcn_s_setprio(0);
        if constexpr (EPI == 0) {
            VMCNT6;                      // retires A0(t+1)(4)+B0(t+1)(2)
            writeA(fA0, nb, 0, t + 1);
            LGKM0;
        } else {
            VMCNT4;                      // retires A0(t+1),B0(t+1)
        }
        BARRIER;
    }

    // ---- peeled tile 15 (buf 1): no staging ----
    {
        const int cb = 1;
        #pragma unroll
        for (int mi = 0; mi < 4; ++mi)
            #pragma unroll
            for (int kk = 0; kk < 2; ++kk) a0[mi][kk] = rdA(cb, mi, kk);
        #pragma unroll
        for (int ni = 0; ni < 2; ++ni)
            #pragma unroll
            for (int kk = 0; kk < 2; ++kk) b0[ni][kk] = rdB(cb, ni, kk);
        #pragma unroll
        for (int mi = 0; mi < 4; ++mi)
            #pragma unroll
            for (int ni = 0; ni < 2; ++ni)
                #pragma unroll
                for (int kk = 0; kk < 2; ++kk)
                    acc[mi][ni] = __builtin_amdgcn_mfma_f32_16x16x32_bf16(a0[mi][kk], b0[ni][kk], acc[mi][ni], 0, 0, 0);
        VMCNT0;   // one-time drain: B1(15), A1(15) (and stores)
        if constexpr (EPI == 0) { writeA(fA1, cb, 1, 15); LGKM0; }
        BARRIER;
        #pragma unroll
        for (int ni = 0; ni < 2; ++ni)
            #pragma unroll
            for (int kk = 0; kk < 2; ++kk) b1[ni][kk] = rdB(cb, ni + 2, kk);
        #pragma unroll
        for (int mi = 0; mi < 4; ++mi)
            #pragma unroll
            for (int kk = 0; kk < 2; ++kk) a1[mi][kk] = rdA(cb, mi + 4, kk);
        #pragma unroll
        for (int mi = 0; mi < 4; ++mi)
            #pragma unroll
            for (int ni = 0; ni < 2; ++ni)
                #pragma unroll
                for (int kk = 0; kk < 2; ++kk) {
                    acc[mi][ni + 2]     = __builtin_amdgcn_mfma_f32_16x16x32_bf16(a0[mi][kk], b1[ni][kk], acc[mi][ni + 2], 0, 0, 0);
                    acc[mi + 4][ni]     = __builtin_amdgcn_mfma_f32_16x16x32_bf16(a1[mi][kk], b0[ni][kk], acc[mi + 4][ni], 0, 0, 0);
                    acc[mi + 4][ni + 2] = __builtin_amdgcn_mfma_f32_16x16x32_bf16(a1[mi][kk], b1[ni][kk], acc[mi + 4][ni + 2], 0, 0, 0);
                }
    }

    // ---- epilogue ----
    int rr = lane >> 4;
    if constexpr (EPI == 0) {
        int bidx = m0 >> 12;
        #pragma unroll
        for (int ni = 0; ni < 4; ++ni) {
            int col = n0 + wn + ni * 64 + lr;
            float hkv = hk[(size_t)bidx * DDIM + col];
            #pragma unroll
            for (int mi = 0; mi < 8; ++mi)
                #pragma unroll
                for (int j = 0; j < 4; ++j) {
                    int row = m0 + wm + mi * 32 + rr * 4 + j;
                    Out[(size_t)row * DDIM + col] = f2bf(fast_tanh(acc[mi][ni][j] + hkv));
                }
        }
    } else {
        // scores bounded: |s| <= sum|V| <= 32, exp finite; bf16 keeps f32 exp range
        #pragma unroll
        for (int ni = 0; ni < 4; ++ni) {
            int col = n0 + wn + ni * 64 + lr;
            #pragma unroll
            for (int mi = 0; mi < 8; ++mi)
                #pragma unroll
                for (int j = 0; j < 4; ++j) {
                    int row = m0 + wm + mi * 32 + rr * 4 + j;
                    Out[(size_t)row * DDIM + col] = f2bf(__expf(acc[mi][ni][j]));
                }
        }
    }
}

// ---------------- normalize E + weighted partial sum, wave-per-row ----------------
// QBF==1: q read as bf16 from qb (ws layout); QBF==0: q read as f32 (fallback)
template<int QBF>
__global__ __launch_bounds__(256) void softmax_wsum_kernel(const short* __restrict__ E,
                                                           float* __restrict__ weights,
                                                           const float* __restrict__ q,
                                                           const short* __restrict__ qb,
                                                           float* __restrict__ partials) {
    int blk   = blockIdx.x;
    int b     = blk >> 8;
    int chunk = blk & 255;
    int tid   = threadIdx.x;
    int lane  = tid & 63, wid = tid >> 6;

    float pv[2][8] = {};
    size_t rowbase = ((size_t)b * SEQ + (size_t)chunk * 16 + (size_t)wid * 4) * DDIM;
    #pragma unroll 1
    for (int r = 0; r < 4; ++r) {
        const short* ep = E + rowbase + (size_t)r * DDIM;
        float x[2][8];
        float ls = 0.f;
        #pragma unroll
        for (int kk = 0; kk < 2; ++kk) {
            short8 v = *(const short8*)(ep + lane * 8 + kk * 512);
            #pragma unroll
            for (int j = 0; j < 8; ++j) { x[kk][j] = bf2f(v[j]); ls += x[kk][j]; }
        }
        #pragma unroll
        for (int o = 32; o > 0; o >>= 1) ls += __shfl_xor(ls, o);
        float inv = 1.f / ls;
        float* wp = weights + rowbase + (size_t)r * DDIM;
        #pragma unroll
        for (int kk = 0; kk < 2; ++kk) {
            int d = lane * 8 + kk * 512;
            float w[8];
            #pragma unroll
            for (int j = 0; j < 8; ++j) w[j] = x[kk][j] * inv;
            *(float4*)(wp + d)     = make_float4(w[0], w[1], w[2], w[3]);
            *(float4*)(wp + d + 4) = make_float4(w[4], w[5], w[6], w[7]);
            if constexpr (QBF) {
                short8 qv = *(const short8*)(qb + rowbase + (size_t)r * DDIM + d);
                #pragma unroll
                for (int j = 0; j < 8; ++j) pv[kk][j] += w[j] * bf2f(qv[j]);
            } else {
                const float* qp = q + rowbase + (size_t)r * DDIM;
                float4 q4a = *(const float4*)(qp + d);
                float4 q4b = *(const float4*)(qp + d + 4);
                pv[kk][0] += w[0] * q4a.x; pv[kk][1] += w[1] * q4a.y;
                pv[kk][2] += w[2] * q4a.z; pv[kk][3] += w[3] * q4a.w;
                pv[kk][4] += w[4] * q4b.x; pv[kk][5] += w[5] * q4b.y;
                pv[kk][6] += w[6] * q4b.z; pv[kk][7] += w[7] * q4b.w;
            }
        }
    }

    __shared__ float red[4][DDIM];
    #pragma unroll
    for (int kk = 0; kk < 2; ++kk) {
        int d = lane * 8 + kk * 512;
        *(float4*)(&red[wid][d])     = *(float4*)(&pv[kk][0]);
        *(float4*)(&red[wid][d + 4]) = *(float4*)(&pv[kk][4]);
    }
    __syncthreads();
    {
        int d = tid * 4;
        float4 s0 = *(float4*)(&red[0][d]);
        float4 s1 = *(float4*)(&red[1][d]);
        float4 s2 = *(float4*)(&red[2][d]);
        float4 s3 = *(float4*)(&red[3][d]);
        float4 o;
        o.x = s0.x + s1.x + s2.x + s3.x;
        o.y = s0.y + s1.y + s2.y + s3.y;
        o.z = s0.z + s1.z + s2.z + s3.z;
        o.w = s0.w + s1.w + s2.w + s3.w;
        *(float4*)(partials + (size_t)blk * DDIM + d) = o;
    }
}

// ---------------- reduce partials -> values ----------------
__global__ __launch_bounds__(256) void reduce_values_kernel(const float* __restrict__ partials,
                                                            float* __restrict__ values) {
    int gid = blockIdx.x * 256 + threadIdx.x;
    int b = gid >> 10, v = gid & 1023;
    float s = 0.f;
    for (int c = 0; c < 256; ++c)
        s += partials[((size_t)b * 256 + c) * DDIM + v];
    values[gid] = s;
}

extern "C" void kernel_launch(void* const* d_in, const int* in_sizes, int n_in,
                              void* d_out, int out_size, void* d_ws, size_t ws_size,
                              hipStream_t stream) {
    const float* q  = (const float*)d_in[0];
    const float* k  = (const float*)d_in[1];
    const float* W1 = (const float*)d_in[2];
    const float* W2 = (const float*)d_in[3];
    const float* V  = (const float*)d_in[4];

    float* values  = (float*)d_out;
    float* weights = (float*)d_out + (size_t)BATCH * DDIM;

    const size_t hk_b   = (((size_t)BATCH * DDIM * 4) + 255) & ~(size_t)255;
    const size_t wT_b   = (size_t)DDIM * DDIM * 2;
    const size_t big_b  = (size_t)MROWS * DDIM * 2;      // 64 MiB (bf16 [MROWS][DDIM])
    const size_t part_b = (size_t)2048 * DDIM * 4;       // 8 MiB
    const size_t need_qbf_ws = hk_b + 2 * wT_b + 2 * big_b + part_b;  // ~146 MB

    char* ws = (char*)d_ws;
    float* hk  = (float*)ws;  ws += hk_b;
    short* W1T = (short*)ws;  ws += wT_b;
    short* VT  = (short*)ws;  ws += wT_b;
    short* E   = (short*)ws;  ws += big_b;               // exp(scores) bf16

    short* q_bf;
    float* partials;
    bool qbf_in_ws = (ws_size >= need_qbf_ws);
    if (qbf_in_ws) {
        q_bf = (short*)ws;    ws += big_b;               // written by GEMM1, read by softmax
        partials = (float*)ws;
    } else {
        // fallback: q_bf in output slab (dead until weights written); softmax reads f32 q
        q_bf = (short*)weights;
        partials = (float*)ws;
    }
    short* H = (short*)weights + (qbf_in_ws ? 0 : (size_t)MROWS * DDIM); // slab, dead pre-softmax

    prep_kernel<<<dim3(2176), dim3(256), 0, stream>>>(W1, W1T, V, VT, k, W2, hk);
    gemm256_kernel<0><<<dim3(512), dim3(512), 0, stream>>>((const void*)q, W1T, hk, H, q_bf);
    gemm256_kernel<1><<<dim3(512), dim3(512), 0, stream>>>((const void*)H, VT, nullptr, E, nullptr);
    if (qbf_in_ws)
        softmax_wsum_kernel<1><<<dim3(2048), dim3(256), 0, stream>>>(E, weights, q, q_bf, partials);
    else
        softmax_wsum_kernel<0><<<dim3(2048), dim3(256), 0, stream>>>(E, weights, q, q_bf, partials);
    reduce_values_kernel<<<dim3(32), dim3(256), 0, stream>>>(partials, values);
}

// Round 8
// 258.378 us; speedup vs baseline: 1.0428x; 1.0428x over previous
//
#include <hip/hip_runtime.h>
#include <hip/hip_bf16.h>

#define DDIM 1024
#define BATCH 8
#define SEQ 4096
#define MROWS (BATCH*SEQ)

typedef __attribute__((ext_vector_type(8))) short short8;
typedef __attribute__((ext_vector_type(4))) float floatx4;

// manual f32 -> bf16 round-to-nearest-even (finite inputs only)
__device__ inline short f2bf(float f) {
    unsigned int u = __builtin_bit_cast(unsigned int, f);
    unsigned int r = (u + 0x7fffu + ((u >> 16) & 1u)) >> 16;
    return (short)r;
}
__device__ inline float bf2f(short s) {
    unsigned int u = ((unsigned int)(unsigned short)s) << 16;
    return __builtin_bit_cast(float, u);
}

__device__ inline float fast_tanh(float x) {
    float e = __expf(2.f * x);          // overflow->inf fine: 1-2/inf = 1
    return 1.f - 2.f / (e + 1.f);
}

typedef const __attribute__((address_space(1))) unsigned int* gas_ptr;
typedef __attribute__((address_space(3))) unsigned int* las_ptr;
__device__ __forceinline__ void gl16(const short* g, short* l) {
    __builtin_amdgcn_global_load_lds((gas_ptr)g, (las_ptr)l, 16, 0, 0);
}

#define VMCNT4 asm volatile("s_waitcnt vmcnt(4)" ::: "memory")
#define VMCNT0 asm volatile("s_waitcnt vmcnt(0)" ::: "memory")
#define BARRIER do { __builtin_amdgcn_sched_barrier(0); __builtin_amdgcn_s_barrier(); \
                     __builtin_amdgcn_sched_barrier(0); } while (0)

// ---------------- fused prep: q->bf16 | W1^T->bf16 | V^T->bf16 | hk ----------------
// blocks [0,2048): convert q; [2048,3072): W1T; [3072,4096): VT; [4096,4224): hk
__global__ __launch_bounds__(256) void prep_kernel(const float* __restrict__ q,
                                                   short* __restrict__ qb,
                                                   const float* __restrict__ W1,
                                                   short* __restrict__ W1T,
                                                   const float* __restrict__ V,
                                                   short* __restrict__ VT,
                                                   const float* __restrict__ k,
                                                   const float* __restrict__ W2,
                                                   float* __restrict__ hk) {
    int bid = blockIdx.x;
    if (bid < 2048) {
        size_t t = (size_t)bid * 256 + threadIdx.x;
        const size_t stride = (size_t)2048 * 256;
        for (int it = 0; it < 8; ++it, t += stride) {
            size_t i = t * 8;
            float4 f0 = *(const float4*)(q + i);
            float4 f1 = *(const float4*)(q + i + 4);
            short8 v;
            v[0]=f2bf(f0.x); v[1]=f2bf(f0.y); v[2]=f2bf(f0.z); v[3]=f2bf(f0.w);
            v[4]=f2bf(f1.x); v[5]=f2bf(f1.y); v[6]=f2bf(f1.z); v[7]=f2bf(f1.w);
            *(short8*)(qb + i) = v;
        }
    } else if (bid < 4096) {
        const float* src = (bid < 3072) ? W1 : V;
        short* dst = (bid < 3072) ? W1T : VT;
        int tb = (bid - 2048) & 1023;
        __shared__ float t[32][33];
        int bx = tb & 31, by = tb >> 5;
        int c  = threadIdx.x & 31;
        int r0 = threadIdx.x >> 5;
        for (int p = 0; p < 4; ++p) {
            int r = p * 8 + r0;
            t[r][c] = src[(size_t)(by * 32 + r) * DDIM + bx * 32 + c];
        }
        __syncthreads();
        for (int p = 0; p < 4; ++p) {
            int r = p * 8 + r0;
            dst[(size_t)(bx * 32 + r) * DDIM + by * 32 + c] = f2bf(t[c][r]);
        }
    } else {
        int hb = bid - 4096;
        int b  = hb >> 4;
        int h0 = (hb & 15) * 64;
        int hl = threadIdx.x & 63;
        int dc = threadIdx.x >> 6;
        const float* kb = k + (size_t)b * DDIM;
        float sum = 0.f;
        for (int d = dc * 256; d < dc * 256 + 256; ++d)
            sum += kb[d] * W2[(size_t)d * DDIM + h0 + hl];
        __shared__ float red[4][64];
        red[dc][hl] = sum;
        __syncthreads();
        if (dc == 0)
            hk[(size_t)b * DDIM + h0 + hl] = red[0][hl] + red[1][hl] + red[2][hl] + red[3][hl];
    }
}

// ---------------- 256x256 8-wave phase-split GEMM with counted vmcnt ----------------
// C[m][n] = sum_k A[m][k] * Bt[n][k], A/Bt bf16.
// EPI==0: out = H (bf16) = tanh(acc + hk[b][n]);  EPI==1: out = E (bf16) = exp(acc)
template<int EPI>
__global__ __launch_bounds__(512, 2) void gemm256_kernel(const short* __restrict__ A,
                                                         const short* __restrict__ Bt,
                                                         const float* __restrict__ hk,
                                                         short* __restrict__ Out) {
    __shared__ __align__(16) short lds[2 * 32768];
    int bid = blockIdx.x;                 // 512 blocks, 512 % 8 == 0
    int swz = (bid & 7) * 64 + (bid >> 3);
    int mt = swz >> 2, nt = swz & 3;
    int m0 = mt * 256, n0 = nt * 256;
    int tid = threadIdx.x, lane = tid & 63, wid = tid >> 6;
    int wm = (wid >> 2) * 16;             // 0 | 16
    int wn = (wid & 3) * 16;              // 0,16,32,48
    int lr = lane & 15, kb = lane >> 4;   // kb 0..3
    floatx4 acc[8][4] = {};               // [mi][ni]

    int srow = lane >> 3;                 // 0..7
    int sblk = (lane & 7) ^ srow;         // pre-swizzled 16B source block
    const size_t arow_base = (size_t)(m0 + wid * 8 + srow) * DDIM + sblk * 8;
    const size_t brow_base = (size_t)(n0 + wid * 8 + srow) * DDIM + sblk * 8;
    const int lds_st = wid * 512 + lane * 8;

    auto stage = [&](int buf, int isB, int h, int t) {
        const short* src = isB ? Bt : A;
        size_t rb = isB ? brow_base : arow_base;
        #pragma unroll
        for (int r = 0; r < 2; ++r)
            gl16(src + rb + (size_t)(h * 128 + r * 64) * DDIM + t * 64,
                 lds + buf * 32768 + isB * 16384 + h * 8192 + r * 4096 + lds_st);
    };
    auto rdA = [&](int buf, int mi, int kk) -> short8 {
        int row = wm + mi * 32 + lr;
        return *(const short8*)(lds + buf * 32768 + (row >> 7) * 8192 +
                                (row & 127) * 64 + (((kk * 4 + kb) ^ (row & 7)) * 8));
    };
    auto rdB = [&](int buf, int ni, int kk) -> short8 {
        int row = wn + ni * 64 + lr;
        return *(const short8*)(lds + buf * 32768 + 16384 + (row >> 7) * 8192 +
                                (row & 127) * 64 + (((kk * 4 + kb) ^ (row & 7)) * 8));
    };

    // prologue: tile 0 halves in first-use order A0,B0,B1,A1
    stage(0, 0, 0, 0); stage(0, 1, 0, 0); stage(0, 1, 1, 0); stage(0, 0, 1, 0);
    VMCNT4;
    BARRIER;

    short8 a0[4][2], a1[4][2], b0[2][2], b1[2][2];

    for (int t = 0; t < 15; ++t) {
        int cb = t & 1, nb = cb ^ 1;
        // ---- P1: (mi0-3 x ni0-1), stage A0(t+1) ----
        stage(nb, 0, 0, t + 1);
        #pragma unroll
        for (int mi = 0; mi < 4; ++mi)
            #pragma unroll
            for (int kk = 0; kk < 2; ++kk) a0[mi][kk] = rdA(cb, mi, kk);
        #pragma unroll
        for (int ni = 0; ni < 2; ++ni)
            #pragma unroll
            for (int kk = 0; kk < 2; ++kk) b0[ni][kk] = rdB(cb, ni, kk);
        __builtin_amdgcn_s_setprio(1);
        #pragma unroll
        for (int mi = 0; mi < 4; ++mi)
            #pragma unroll
            for (int ni = 0; ni < 2; ++ni)
                #pragma unroll
                for (int kk = 0; kk < 2; ++kk)
                    acc[mi][ni] = __builtin_amdgcn_mfma_f32_16x16x32_bf16(a0[mi][kk], b0[ni][kk], acc[mi][ni], 0, 0, 0);
        __builtin_amdgcn_s_setprio(0);
        VMCNT4;
        BARRIER;
        // ---- P2: (mi0-3 x ni2-3), stage B0(t+1) ----
        stage(nb, 1, 0, t + 1);
        #pragma unroll
        for (int ni = 0; ni < 2; ++ni)
            #pragma unroll
            for (int kk = 0; kk < 2; ++kk) b1[ni][kk] = rdB(cb, ni + 2, kk);
        __builtin_amdgcn_s_setprio(1);
        #pragma unroll
        for (int mi = 0; mi < 4; ++mi)
            #pragma unroll
            for (int ni = 0; ni < 2; ++ni)
                #pragma unroll
                for (int kk = 0; kk < 2; ++kk)
                    acc[mi][ni + 2] = __builtin_amdgcn_mfma_f32_16x16x32_bf16(a0[mi][kk], b1[ni][kk], acc[mi][ni + 2], 0, 0, 0);
        __builtin_amdgcn_s_setprio(0);
        VMCNT4;
        BARRIER;
        // ---- P3: (mi4-7 x ni0-1), stage B1(t+1) ----
        stage(nb, 1, 1, t + 1);
        #pragma unroll
        for (int mi = 0; mi < 4; ++mi)
            #pragma unroll
            for (int kk = 0; kk < 2; ++kk) a1[mi][kk] = rdA(cb, mi + 4, kk);
        __builtin_amdgcn_s_setprio(1);
        #pragma unroll
        for (int mi = 0; mi < 4; ++mi)
            #pragma unroll
            for (int ni = 0; ni < 2; ++ni)
                #pragma unroll
                for (int kk = 0; kk < 2; ++kk)
                    acc[mi + 4][ni] = __builtin_amdgcn_mfma_f32_16x16x32_bf16(a1[mi][kk], b0[ni][kk], acc[mi + 4][ni], 0, 0, 0);
        __builtin_amdgcn_s_setprio(0);
        BARRIER;
        // ---- P4: (mi4-7 x ni2-3), stage A1(t+1) ----
        stage(nb, 0, 1, t + 1);
        __builtin_amdgcn_s_setprio(1);
        #pragma unroll
        for (int mi = 0; mi < 4; ++mi)
            #pragma unroll
            for (int ni = 0; ni < 2; ++ni)
                #pragma unroll
                for (int kk = 0; kk < 2; ++kk)
                    acc[mi + 4][ni + 2] = __builtin_amdgcn_mfma_f32_16x16x32_bf16(a1[mi][kk], b1[ni][kk], acc[mi + 4][ni + 2], 0, 0, 0);
        __builtin_amdgcn_s_setprio(0);
        VMCNT4;
        BARRIER;
    }

    // ---- peeled tile 15 (buf 1): no staging ----
    {
        const int cb = 1;
        #pragma unroll
        for (int mi = 0; mi < 4; ++mi)
            #pragma unroll
            for (int kk = 0; kk < 2; ++kk) a0[mi][kk] = rdA(cb, mi, kk);
        #pragma unroll
        for (int ni = 0; ni < 2; ++ni)
            #pragma unroll
            for (int kk = 0; kk < 2; ++kk) b0[ni][kk] = rdB(cb, ni, kk);
        #pragma unroll
        for (int mi = 0; mi < 4; ++mi)
            #pragma unroll
            for (int ni = 0; ni < 2; ++ni)
                #pragma unroll
                for (int kk = 0; kk < 2; ++kk)
                    acc[mi][ni] = __builtin_amdgcn_mfma_f32_16x16x32_bf16(a0[mi][kk], b0[ni][kk], acc[mi][ni], 0, 0, 0);
        VMCNT0;
        BARRIER;
        #pragma unroll
        for (int ni = 0; ni < 2; ++ni)
            #pragma unroll
            for (int kk = 0; kk < 2; ++kk) b1[ni][kk] = rdB(cb, ni + 2, kk);
        #pragma unroll
        for (int mi = 0; mi < 4; ++mi)
            #pragma unroll
            for (int kk = 0; kk < 2; ++kk) a1[mi][kk] = rdA(cb, mi + 4, kk);
        #pragma unroll
        for (int mi = 0; mi < 4; ++mi)
            #pragma unroll
            for (int ni = 0; ni < 2; ++ni)
                #pragma unroll
                for (int kk = 0; kk < 2; ++kk) {
                    acc[mi][ni + 2]     = __builtin_amdgcn_mfma_f32_16x16x32_bf16(a0[mi][kk], b1[ni][kk], acc[mi][ni + 2], 0, 0, 0);
                    acc[mi + 4][ni]     = __builtin_amdgcn_mfma_f32_16x16x32_bf16(a1[mi][kk], b0[ni][kk], acc[mi + 4][ni], 0, 0, 0);
                    acc[mi + 4][ni + 2] = __builtin_amdgcn_mfma_f32_16x16x32_bf16(a1[mi][kk], b1[ni][kk], acc[mi + 4][ni + 2], 0, 0, 0);
                }
    }

    // ---- epilogue ----
    int rr = lane >> 4;
    if constexpr (EPI == 0) {
        int bidx = m0 >> 12;
        #pragma unroll
        for (int ni = 0; ni < 4; ++ni) {
            int col = n0 + wn + ni * 64 + lr;
            float hkv = hk[(size_t)bidx * DDIM + col];
            #pragma unroll
            for (int mi = 0; mi < 8; ++mi)
                #pragma unroll
                for (int j = 0; j < 4; ++j) {
                    int row = m0 + wm + mi * 32 + rr * 4 + j;
                    Out[(size_t)row * DDIM + col] = f2bf(fast_tanh(acc[mi][ni][j] + hkv));
                }
        }
    } else {
        // scores bounded: |s| <= sum|V| <= 32, exp finite; bf16 keeps f32 exp range
        #pragma unroll
        for (int ni = 0; ni < 4; ++ni) {
            int col = n0 + wn + ni * 64 + lr;
            #pragma unroll
            for (int mi = 0; mi < 8; ++mi)
                #pragma unroll
                for (int j = 0; j < 4; ++j) {
                    int row = m0 + wm + mi * 32 + rr * 4 + j;
                    Out[(size_t)row * DDIM + col] = f2bf(__expf(acc[mi][ni][j]));
                }
        }
    }
}

// ---------------- normalize E + weighted partial sum, wave-per-row ----------------
// E = exp(scores) bf16 [MROWS][DDIM]; weights = E/rowsum (f32, output);
// partials[blk][d] = sum over block rows of weights*q
// QBF==1: q read as bf16 from qb (ws layout); QBF==0: q read as f32 (fallback)
template<int QBF>
__global__ __launch_bounds__(256) void softmax_wsum_kernel(const short* __restrict__ E,
                                                           float* __restrict__ weights,
                                                           const float* __restrict__ q,
                                                           const short* __restrict__ qb,
                                                           float* __restrict__ partials) {
    int blk   = blockIdx.x;
    int b     = blk >> 8;
    int chunk = blk & 255;
    int tid   = threadIdx.x;
    int lane  = tid & 63, wid = tid >> 6;

    float pv[2][8] = {};
    size_t rowbase = ((size_t)b * SEQ + (size_t)chunk * 16 + (size_t)wid * 4) * DDIM;
    #pragma unroll 1
    for (int r = 0; r < 4; ++r) {
        const short* ep = E + rowbase + (size_t)r * DDIM;
        float x[2][8];
        float ls = 0.f;
        #pragma unroll
        for (int kk = 0; kk < 2; ++kk) {
            short8 v = *(const short8*)(ep + lane * 8 + kk * 512);
            #pragma unroll
            for (int j = 0; j < 8; ++j) { x[kk][j] = bf2f(v[j]); ls += x[kk][j]; }
        }
        #pragma unroll
        for (int o = 32; o > 0; o >>= 1) ls += __shfl_xor(ls, o);
        float inv = 1.f / ls;
        float* wp = weights + rowbase + (size_t)r * DDIM;
        #pragma unroll
        for (int kk = 0; kk < 2; ++kk) {
            int d = lane * 8 + kk * 512;
            float w[8];
            #pragma unroll
            for (int j = 0; j < 8; ++j) w[j] = x[kk][j] * inv;
            *(float4*)(wp + d)     = make_float4(w[0], w[1], w[2], w[3]);
            *(float4*)(wp + d + 4) = make_float4(w[4], w[5], w[6], w[7]);
            if constexpr (QBF) {
                short8 qv = *(const short8*)(qb + rowbase + (size_t)r * DDIM + d);
                #pragma unroll
                for (int j = 0; j < 8; ++j) pv[kk][j] += w[j] * bf2f(qv[j]);
            } else {
                const float* qp = q + rowbase + (size_t)r * DDIM;
                float4 q4a = *(const float4*)(qp + d);
                float4 q4b = *(const float4*)(qp + d + 4);
                pv[kk][0] += w[0] * q4a.x; pv[kk][1] += w[1] * q4a.y;
                pv[kk][2] += w[2] * q4a.z; pv[kk][3] += w[3] * q4a.w;
                pv[kk][4] += w[4] * q4b.x; pv[kk][5] += w[5] * q4b.y;
                pv[kk][6] += w[6] * q4b.z; pv[kk][7] += w[7] * q4b.w;
            }
        }
    }

    __shared__ float red[4][DDIM];
    #pragma unroll
    for (int kk = 0; kk < 2; ++kk) {
        int d = lane * 8 + kk * 512;
        *(float4*)(&red[wid][d])     = *(float4*)(&pv[kk][0]);
        *(float4*)(&red[wid][d + 4]) = *(float4*)(&pv[kk][4]);
    }
    __syncthreads();
    {
        int d = tid * 4;
        float4 s0 = *(float4*)(&red[0][d]);
        float4 s1 = *(float4*)(&red[1][d]);
        float4 s2 = *(float4*)(&red[2][d]);
        float4 s3 = *(float4*)(&red[3][d]);
        float4 o;
        o.x = s0.x + s1.x + s2.x + s3.x;
        o.y = s0.y + s1.y + s2.y + s3.y;
        o.z = s0.z + s1.z + s2.z + s3.z;
        o.w = s0.w + s1.w + s2.w + s3.w;
        *(float4*)(partials + (size_t)blk * DDIM + d) = o;
    }
}

// ---------------- reduce partials -> values ----------------
__global__ __launch_bounds__(256) void reduce_values_kernel(const float* __restrict__ partials,
                                                            float* __restrict__ values) {
    int gid = blockIdx.x * 256 + threadIdx.x;
    int b = gid >> 10, v = gid & 1023;
    float s = 0.f;
    for (int c = 0; c < 256; ++c)
        s += partials[((size_t)b * 256 + c) * DDIM + v];
    values[gid] = s;
}

extern "C" void kernel_launch(void* const* d_in, const int* in_sizes, int n_in,
                              void* d_out, int out_size, void* d_ws, size_t ws_size,
                              hipStream_t stream) {
    const float* q  = (const float*)d_in[0];
    const float* k  = (const float*)d_in[1];
    const float* W1 = (const float*)d_in[2];
    const float* W2 = (const float*)d_in[3];
    const float* V  = (const float*)d_in[4];

    float* values  = (float*)d_out;
    float* weights = (float*)d_out + (size_t)BATCH * DDIM;

    const size_t hk_b   = (((size_t)BATCH * DDIM * 4) + 255) & ~(size_t)255;
    const size_t wT_b   = (size_t)DDIM * DDIM * 2;
    const size_t big_b  = (size_t)MROWS * DDIM * 2;      // 64 MiB (bf16 [MROWS][DDIM])
    const size_t part_b = (size_t)2048 * DDIM * 4;       // 8 MiB
    const size_t need_qbf_ws = hk_b + 2 * wT_b + 2 * big_b + part_b;  // ~146 MB

    char* ws = (char*)d_ws;
    float* hk  = (float*)ws;  ws += hk_b;
    short* W1T = (short*)ws;  ws += wT_b;
    short* VT  = (short*)ws;  ws += wT_b;
    short* E   = (short*)ws;  ws += big_b;               // exp(scores) bf16

    short* q_bf;
    float* partials;
    bool qbf_in_ws = (ws_size >= need_qbf_ws);
    if (qbf_in_ws) {
        q_bf = (short*)ws;    ws += big_b;               // survives until softmax
        partials = (float*)ws;
    } else {
        // fallback: q_bf in output slab (dead before weights written); softmax reads f32 q
        q_bf = (short*)weights;
        partials = (float*)ws;
    }
    short* H = (short*)weights + (qbf_in_ws ? 0 : (size_t)MROWS * DDIM); // slab storage, dead pre-softmax

    prep_kernel<<<dim3(4224), dim3(256), 0, stream>>>(q, q_bf, W1, W1T, V, VT, k, W2, hk);
    gemm256_kernel<0><<<dim3(512), dim3(512), 0, stream>>>(q_bf, W1T, hk, H);
    gemm256_kernel<1><<<dim3(512), dim3(512), 0, stream>>>(H, VT, nullptr, E);
    if (qbf_in_ws)
        softmax_wsum_kernel<1><<<dim3(2048), dim3(256), 0, stream>>>(E, weights, q, q_bf, partials);
    else
        softmax_wsum_kernel<0><<<dim3(2048), dim3(256), 0, stream>>>(E, weights, q, q_bf, partials);
    reduce_values_kernel<<<dim3(32), dim3(256), 0, stream>>>(partials, values);
}